// Round 1
// baseline (150.211 us; speedup 1.0000x reference)
//
#include <hip/hip_runtime.h>

typedef __bf16 bf16;
typedef __bf16 bf16x8 __attribute__((ext_vector_type(8)));
typedef __bf16 bf16x4 __attribute__((ext_vector_type(4)));
typedef float  f32x4  __attribute__((ext_vector_type(4)));

static constexpr int NB = 8;     // batch
static constexpr int NH = 12;    // heads
static constexpr int HD = 32;    // head dim
static constexpr int NN = 1024;  // tokens (32x32)
static constexpr int NC = 384;   // channels
static constexpr int NTBL = 3969; // (2*32-1)^2

static constexpr size_t XB_N   = (size_t)NB*NC*NN;    // x in bf16
static constexpr size_t WQKV_N = (size_t)3*NC*NC;     // [wq;wkv] 1152x384
static constexpr size_t WP_N   = (size_t)NC*NC;       // wproj
static constexpr size_t QKV_N  = (size_t)NB*NH*NN*HD; // per tensor

static constexpr size_t XB_OFF   = 0;
static constexpr size_t WQKV_OFF = XB_OFF + XB_N;
static constexpr size_t WP_OFF   = WQKV_OFF + WQKV_N;
static constexpr size_t Q_OFF    = WP_OFF + WP_N;
static constexpr size_t K_OFF    = Q_OFF + QKV_N;
static constexpr size_t V_OFF    = K_OFF + QKV_N;
static constexpr size_t AO_OFF   = V_OFF + QKV_N;

#define MFMA16(a,b,c) __builtin_amdgcn_mfma_f32_16x16x32_bf16(a,b,c,0,0,0)

// ---------------- casts ----------------
__global__ __launch_bounds__(256) void cast_x_kernel(const float* __restrict__ x,
                                                     bf16* __restrict__ xb)
{
    const size_t i = ((size_t)blockIdx.x * 256 + threadIdx.x) * 4;
    if (i >= XB_N) return;
    float4 v = *(const float4*)(x + i);
    bf16x4 o; o[0] = (bf16)v.x; o[1] = (bf16)v.y; o[2] = (bf16)v.z; o[3] = (bf16)v.w;
    *(bf16x4*)(xb + i) = o;
}

__global__ __launch_bounds__(256) void cast_w_kernel(const float* __restrict__ wq,
                                                     const float* __restrict__ wkv,
                                                     const float* __restrict__ wproj,
                                                     bf16* __restrict__ wqkv,
                                                     bf16* __restrict__ wp)
{
    const size_t i = ((size_t)blockIdx.x * 256 + threadIdx.x) * 4;
    if (i >= WQKV_N + WP_N) return;
    const float* src; bf16* dst;
    if (i < (size_t)NC*NC)      { src = wq + i;                     dst = wqkv + i; }
    else if (i < WQKV_N)        { src = wkv + (i - (size_t)NC*NC);  dst = wqkv + i; }
    else                        { src = wproj + (i - WQKV_N);       dst = wp + (i - WQKV_N); }
    float4 v = *(const float4*)src;
    bf16x4 o; o[0] = (bf16)v.x; o[1] = (bf16)v.y; o[2] = (bf16)v.z; o[3] = (bf16)v.w;
    *(bf16x4*)dst = o;
}

// ---------------- QKV projection GEMM ----------------
// out[o,n] = sum_c Wqkv[o,c] * X[b,c,n] ; o in [0,1152)
// scatter: o<384 -> Q[b][h][n][d], o<768 -> K[b][h][n][d], else V[b][h][d][n]
__global__ __launch_bounds__(256) void qkv_gemm_kernel(
    const bf16* __restrict__ W, const bf16* __restrict__ X,
    const float* __restrict__ bq, const float* __restrict__ bkv,
    bf16* __restrict__ Qd, bf16* __restrict__ Kd, bf16* __restrict__ Vd)
{
    __shared__ bf16 As[64][40];   // [o][c] tile
    __shared__ bf16 Bs[64][40];   // [n][c] tile (transposed during staging)
    const int t = threadIdx.x;
    const int w = t >> 6, lane = t & 63, g = lane >> 4, l16 = lane & 15;
    const int wm = w >> 1, wn = w & 1;
    const int n0g = blockIdx.x * 64;
    const int b = n0g >> 10, n0 = n0g & 1023;
    const int o0 = blockIdx.y * 64;
    const bf16* Xb = X + (size_t)b * NC * NN;

    f32x4 acc[2][2] = {};

    for (int k0 = 0; k0 < NC; k0 += 32) {
        __syncthreads();
        { const int r = t >> 2, cc = (t & 3) * 8;
          *(bf16x8*)&As[r][cc] = *(const bf16x8*)&W[(size_t)(o0 + r) * NC + k0 + cc]; }
        { const int cc = t >> 3, ng = (t & 7) * 8;
          bf16x8 v = *(const bf16x8*)&Xb[(size_t)(k0 + cc) * NN + n0 + ng];
#pragma unroll
          for (int e = 0; e < 8; ++e) Bs[ng + e][cc] = v[e]; }
        __syncthreads();
        bf16x8 a0 = *(const bf16x8*)&As[wm*32      + l16][g*8];
        bf16x8 a1 = *(const bf16x8*)&As[wm*32 + 16 + l16][g*8];
        bf16x8 b0 = *(const bf16x8*)&Bs[wn*32      + l16][g*8];
        bf16x8 b1 = *(const bf16x8*)&Bs[wn*32 + 16 + l16][g*8];
        acc[0][0] = MFMA16(a0, b0, acc[0][0]);
        acc[0][1] = MFMA16(a0, b1, acc[0][1]);
        acc[1][0] = MFMA16(a1, b0, acc[1][0]);
        acc[1][1] = MFMA16(a1, b1, acc[1][1]);
    }

#pragma unroll
    for (int sm = 0; sm < 2; ++sm)
#pragma unroll
    for (int sn = 0; sn < 2; ++sn) {
        const int col   = n0 + wn*32 + sn*16 + l16;
        const int obase = o0 + wm*32 + sm*16 + g*4;  // 4 consecutive o (same head, same group)
        f32x4 v = acc[sm][sn];
        if (obase < 384) {
            const int hh = obase >> 5, d = obase & 31;
            bf16x4 o4;
#pragma unroll
            for (int r = 0; r < 4; ++r) o4[r] = (bf16)(v[r] + bq[obase + r]);
            *(bf16x4*)&Qd[(((size_t)b*NH + hh)*NN + col)*HD + d] = o4;
        } else if (obase < 768) {
            const int oo = obase - 384; const int hh = oo >> 5, d = oo & 31;
            bf16x4 o4;
#pragma unroll
            for (int r = 0; r < 4; ++r) o4[r] = (bf16)(v[r] + bkv[oo + r]);
            *(bf16x4*)&Kd[(((size_t)b*NH + hh)*NN + col)*HD + d] = o4;
        } else {
            const int oo = obase - 768; const int hh = oo >> 5, d = oo & 31;
#pragma unroll
            for (int r = 0; r < 4; ++r)
                Vd[(((size_t)b*NH + hh)*HD + d + r)*NN + col] = (bf16)(v[r] + bkv[obase - 384 + r]);
        }
    }
}

// ---------------- fused flash attention ----------------
// block = (q-tile of 64, head, batch); 4 waves x 16 q-rows.
// relative-position bias computed arithmetically (rel_index input unused);
// per-head bias column staged in LDS (15.9 KB).
__global__ __launch_bounds__(256) void attn_kernel(
    const bf16* __restrict__ Qg, const bf16* __restrict__ Kg, const bf16* __restrict__ Vg,
    const float* __restrict__ bias_table, bf16* __restrict__ AO)
{
    __shared__ float biasc[NTBL];
    __shared__ bf16 Ks[64][40];      // [m][d]
    __shared__ bf16 Vs[32][72];      // [d][m]
    __shared__ bf16 Ps[4][16][72];   // per-wave P tile [n][m]

    const int t = threadIdx.x;
    const int w = t >> 6, lane = t & 63, g = lane >> 4, l16 = lane & 15;
    const int qt = blockIdx.x, h = blockIdx.y, b = blockIdx.z;

    for (int r = t; r < NTBL; r += 256) biasc[r] = bias_table[(size_t)r * NH + h];

    const bf16* Qb = Qg + ((size_t)(b*NH + h)) * NN * HD;
    const bf16* Kb = Kg + ((size_t)(b*NH + h)) * NN * HD;
    const bf16* Vb = Vg + ((size_t)(b*NH + h)) * HD * NN;

    const int q0 = qt * 64;
    const int qn = q0 + w*16 + l16;
    const bf16x8 qfrag = *(const bf16x8*)&Qb[(size_t)qn * HD + g*8];

    f32x4 oacc[2] = {};
    float m_run[4], l_run[4];
#pragma unroll
    for (int r = 0; r < 4; ++r) { m_run[r] = -1e30f; l_run[r] = 0.f; }
    const float scale = 0.17677669529663687f;  // 32^-0.5
    const int nrow_base = q0 + w*16 + g*4;
    const int i1b = nrow_base >> 5;  // q-row i coordinate base (rows 4g..4g+3 share i1 only if aligned; recompute per r)

    for (int m0 = 0; m0 < NN; m0 += 64) {
        __syncthreads();
        { const int mm = t >> 2, dg = (t & 3) * 8;
          *(bf16x8*)&Ks[mm][dg] = *(const bf16x8*)&Kb[(size_t)(m0 + mm)*HD + dg]; }
        { const int d = t >> 3, mg = (t & 7) * 8;
          *(bf16x8*)&Vs[d][mg] = *(const bf16x8*)&Vb[(size_t)d*NN + m0 + mg]; }
        __syncthreads();

        float s[4][4];
#pragma unroll
        for (int sc = 0; sc < 4; ++sc) {
            bf16x8 kf = *(const bf16x8*)&Ks[sc*16 + l16][g*8];
            f32x4 z = {0.f, 0.f, 0.f, 0.f};
            z = MFMA16(qfrag, kf, z);
            const int mcol = m0 + sc*16 + l16;
            const int i2 = mcol >> 5, j2 = mcol & 31;
#pragma unroll
            for (int r = 0; r < 4; ++r) {
                const int nrow = nrow_base + r;
                const int idx = ((nrow >> 5) - i2 + 31) * 63 + ((nrow & 31) - j2 + 31);
                s[sc][r] = z[r] * scale + biasc[idx];
            }
        }
        (void)i1b;
#pragma unroll
        for (int r = 0; r < 4; ++r) {
            float vmax = fmaxf(fmaxf(s[0][r], s[1][r]), fmaxf(s[2][r], s[3][r]));
            vmax = fmaxf(vmax, __shfl_xor(vmax, 1));
            vmax = fmaxf(vmax, __shfl_xor(vmax, 2));
            vmax = fmaxf(vmax, __shfl_xor(vmax, 4));
            vmax = fmaxf(vmax, __shfl_xor(vmax, 8));
            const float mnew = fmaxf(m_run[r], vmax);
            const float corr = __expf(m_run[r] - mnew);
            m_run[r] = mnew;
            float ls = 0.f;
#pragma unroll
            for (int sc = 0; sc < 4; ++sc) { float p = __expf(s[sc][r] - mnew); s[sc][r] = p; ls += p; }
            ls += __shfl_xor(ls, 1); ls += __shfl_xor(ls, 2);
            ls += __shfl_xor(ls, 4); ls += __shfl_xor(ls, 8);
            l_run[r] = l_run[r] * corr + ls;
            oacc[0][r] *= corr; oacc[1][r] *= corr;
        }
#pragma unroll
        for (int sc = 0; sc < 4; ++sc)
#pragma unroll
            for (int r = 0; r < 4; ++r)
                Ps[w][g*4 + r][sc*16 + l16] = (bf16)s[sc][r];

        // per-wave P: same-wave LDS write->read; compiler inserts lgkmcnt wait
#pragma unroll
        for (int kc = 0; kc < 2; ++kc) {
            bf16x8 pf = *(const bf16x8*)&Ps[w][l16][kc*32 + g*8];
#pragma unroll
            for (int ds = 0; ds < 2; ++ds) {
                bf16x8 vf = *(const bf16x8*)&Vs[ds*16 + l16][kc*32 + g*8];
                oacc[ds] = MFMA16(pf, vf, oacc[ds]);
            }
        }
    }

#pragma unroll
    for (int ds = 0; ds < 2; ++ds) {
        const int d = ds*16 + l16;
        bf16x4 o4;
#pragma unroll
        for (int r = 0; r < 4; ++r) o4[r] = (bf16)(oacc[ds][r] / l_run[r]);
        *(bf16x4*)&AO[((size_t)(b*NC) + h*HD + d)*NN + nrow_base] = o4;
    }
}

// ---------------- output projection GEMM ----------------
// out[b,o,n] = sum_m Wp[o,m] * AO[b,m,n] + bproj[o]   (fp32 out)
__global__ __launch_bounds__(256) void proj_gemm_kernel(
    const bf16* __restrict__ W, const bf16* __restrict__ AO,
    const float* __restrict__ bproj, float* __restrict__ out)
{
    __shared__ bf16 As[64][40];
    __shared__ bf16 Bs[64][40];
    const int t = threadIdx.x;
    const int w = t >> 6, lane = t & 63, g = lane >> 4, l16 = lane & 15;
    const int wm = w >> 1, wn = w & 1;
    const int n0g = blockIdx.x * 64;
    const int b = n0g >> 10, n0 = n0g & 1023;
    const int o0 = blockIdx.y * 64;
    const bf16* Ab = AO + (size_t)b * NC * NN;

    f32x4 acc[2][2] = {};

    for (int k0 = 0; k0 < NC; k0 += 32) {
        __syncthreads();
        { const int r = t >> 2, cc = (t & 3) * 8;
          *(bf16x8*)&As[r][cc] = *(const bf16x8*)&W[(size_t)(o0 + r) * NC + k0 + cc]; }
        { const int cc = t >> 3, ng = (t & 7) * 8;
          bf16x8 v = *(const bf16x8*)&Ab[(size_t)(k0 + cc) * NN + n0 + ng];
#pragma unroll
          for (int e = 0; e < 8; ++e) Bs[ng + e][cc] = v[e]; }
        __syncthreads();
        bf16x8 a0 = *(const bf16x8*)&As[wm*32      + l16][g*8];
        bf16x8 a1 = *(const bf16x8*)&As[wm*32 + 16 + l16][g*8];
        bf16x8 b0 = *(const bf16x8*)&Bs[wn*32      + l16][g*8];
        bf16x8 b1 = *(const bf16x8*)&Bs[wn*32 + 16 + l16][g*8];
        acc[0][0] = MFMA16(a0, b0, acc[0][0]);
        acc[0][1] = MFMA16(a0, b1, acc[0][1]);
        acc[1][0] = MFMA16(a1, b0, acc[1][0]);
        acc[1][1] = MFMA16(a1, b1, acc[1][1]);
    }

#pragma unroll
    for (int sm = 0; sm < 2; ++sm)
#pragma unroll
    for (int sn = 0; sn < 2; ++sn) {
        const int col   = n0 + wn*32 + sn*16 + l16;
        const int obase = o0 + wm*32 + sm*16 + g*4;
        f32x4 v = acc[sm][sn];
#pragma unroll
        for (int r = 0; r < 4; ++r)
            out[((size_t)b*NC + obase + r)*NN + col] = v[r] + bproj[obase + r];
    }
}

extern "C" void kernel_launch(void* const* d_in, const int* in_sizes, int n_in,
                              void* d_out, int out_size, void* d_ws, size_t ws_size,
                              hipStream_t stream)
{
    const float* x          = (const float*)d_in[0];
    const float* wq         = (const float*)d_in[1];
    const float* bq         = (const float*)d_in[2];
    const float* wkv        = (const float*)d_in[3];
    const float* bkv        = (const float*)d_in[4];
    const float* wproj      = (const float*)d_in[5];
    const float* bproj      = (const float*)d_in[6];
    const float* bias_table = (const float*)d_in[7];
    // d_in[8] = rel_index: unused (computed arithmetically in-kernel)
    float* out = (float*)d_out;

    bf16* wsb  = (bf16*)d_ws;
    bf16* Xb   = wsb + XB_OFF;
    bf16* Wqkv = wsb + WQKV_OFF;
    bf16* Wp   = wsb + WP_OFF;
    bf16* Qd   = wsb + Q_OFF;
    bf16* Kd   = wsb + K_OFF;
    bf16* Vd   = wsb + V_OFF;
    bf16* AO   = wsb + AO_OFF;

    cast_x_kernel<<<dim3((unsigned)(XB_N/4/256)), 256, 0, stream>>>(x, Xb);
    cast_w_kernel<<<dim3((unsigned)((WQKV_N + WP_N)/4/256)), 256, 0, stream>>>(wq, wkv, wproj, Wqkv, Wp);
    qkv_gemm_kernel<<<dim3(128, 18), 256, 0, stream>>>(Wqkv, Xb, bq, bkv, Qd, Kd, Vd);
    attn_kernel<<<dim3(16, 12, 8), 256, 0, stream>>>(Qd, Kd, Vd, bias_table, AO);
    proj_gemm_kernel<<<dim3(128, 6), 256, 0, stream>>>(Wp, AO, bproj, out);
}

// Round 2
// 127.364 us; speedup vs baseline: 1.1794x; 1.1794x over previous
//
#include <hip/hip_runtime.h>

typedef __bf16 bf16;
typedef __bf16 bf16x8 __attribute__((ext_vector_type(8)));
typedef __bf16 bf16x4 __attribute__((ext_vector_type(4)));
typedef __bf16 bf16x2 __attribute__((ext_vector_type(2)));
typedef float  f32x4  __attribute__((ext_vector_type(4)));

static constexpr int NB = 8;      // batch
static constexpr int NH = 12;     // heads
static constexpr int HD = 32;     // head dim
static constexpr int NN = 1024;   // tokens (32x32)
static constexpr int NC = 384;    // channels
static constexpr int NTBL = 3969; // (2*32-1)^2

static constexpr float LOG2E = 1.4426950408889634f;
static constexpr float QSC   = (float)(0.17677669529663687 * 1.4426950408889634); // scale*log2e

static constexpr size_t XT_N   = (size_t)NB*NN*NC;    // x transposed [b][n][c] bf16
static constexpr size_t WQKV_N = (size_t)3*NC*NC;
static constexpr size_t WP_N   = (size_t)NC*NC;
static constexpr size_t QKV_N  = (size_t)NB*NH*NN*HD;

static constexpr size_t XT_OFF   = 0;
static constexpr size_t WQKV_OFF = XT_OFF + XT_N;
static constexpr size_t WP_OFF   = WQKV_OFF + WQKV_N;
static constexpr size_t Q_OFF    = WP_OFF + WP_N;
static constexpr size_t K_OFF    = Q_OFF + QKV_N;
static constexpr size_t V_OFF    = K_OFF + QKV_N;
static constexpr size_t AO_OFF   = V_OFF + QKV_N;     // [b][n][c] bf16

#define MFMA16(a,b,c) __builtin_amdgcn_mfma_f32_16x16x32_bf16(a,b,c,0,0,0)

// ---------------- cast + transpose x: [b][c][n] f32 -> [b][n][c] bf16 ----------------
__global__ __launch_bounds__(256) void cast_xt_kernel(const float* __restrict__ x,
                                                      bf16* __restrict__ xt)
{
    __shared__ bf16 T[64][68];   // [n][c], stride 136B: phase-2 8B reads ~min-conflict
    const int t = threadIdx.x;
    const int bid = blockIdx.x;            // b*96 + ct*16 + nt
    const int b = bid / 96, rem = bid % 96, ct = rem >> 4, nt = rem & 15;
    const int c0 = ct * 64, n0 = nt * 64;
    const float* Xb = x + (size_t)b * NC * NN;
    const int nl = t & 63, c4 = (t >> 6) * 4;
#pragma unroll
    for (int i = 0; i < 4; ++i) {
        const int c = c4 + i * 16;
        bf16x4 v;
#pragma unroll
        for (int j = 0; j < 4; ++j)
            v[j] = (bf16)Xb[(size_t)(c0 + c + j) * NN + n0 + nl];  // coalesced over nl
        *(bf16x4*)&T[nl][c] = v;
    }
    __syncthreads();
    const int n = t >> 2;
#pragma unroll
    for (int i = 0; i < 2; ++i) {
        const int cg = (t & 3) * 8 + i * 32;
        bf16x4 a = *(const bf16x4*)&T[n][cg];
        bf16x4 bv = *(const bf16x4*)&T[n][cg + 4];
        bf16x8 vv = __builtin_shufflevector(a, bv, 0, 1, 2, 3, 4, 5, 6, 7);
        *(bf16x8*)&xt[((size_t)b * NN + n0 + n) * NC + c0 + cg] = vv;
    }
}

// ---------------- cast weights ----------------
__global__ __launch_bounds__(256) void cast_w_kernel(const float* __restrict__ wq,
                                                     const float* __restrict__ wkv,
                                                     const float* __restrict__ wproj,
                                                     bf16* __restrict__ wqkv,
                                                     bf16* __restrict__ wp)
{
    const size_t i = ((size_t)blockIdx.x * 256 + threadIdx.x) * 4;
    if (i >= WQKV_N + WP_N) return;
    const float* src; bf16* dst;
    if (i < (size_t)NC*NC)      { src = wq + i;                     dst = wqkv + i; }
    else if (i < WQKV_N)        { src = wkv + (i - (size_t)NC*NC);  dst = wqkv + i; }
    else                        { src = wproj + (i - WQKV_N);       dst = wp + (i - WQKV_N); }
    float4 v = *(const float4*)src;
    bf16x4 o; o[0] = (bf16)v.x; o[1] = (bf16)v.y; o[2] = (bf16)v.z; o[3] = (bf16)v.w;
    *(bf16x4*)dst = o;
}

// ---------------- QKV projection GEMM ----------------
// out[o,n] = sum_c Wqkv[o,c] * Xt[n,c] ; Q pre-scaled by scale*log2e
__global__ __launch_bounds__(256) void qkv_gemm_kernel(
    const bf16* __restrict__ W, const bf16* __restrict__ Xt,
    const float* __restrict__ bq, const float* __restrict__ bkv,
    bf16* __restrict__ Qd, bf16* __restrict__ Kd, bf16* __restrict__ Vd)
{
    __shared__ bf16 As[64][40];   // [o][c]
    __shared__ bf16 Bs[64][40];   // [n][c]
    const int t = threadIdx.x;
    const int w = t >> 6, lane = t & 63, g = lane >> 4, l16 = lane & 15;
    const int wm = w >> 1, wn = w & 1;
    const int n0g = blockIdx.x * 64;
    const int b = n0g >> 10, n0 = n0g & 1023;
    const int o0 = blockIdx.y * 64;
    const bf16* Xb = Xt + (size_t)b * NN * NC;

    f32x4 acc[2][2] = {};

    for (int k0 = 0; k0 < NC; k0 += 32) {
        __syncthreads();
        { const int r = t >> 2, cc = (t & 3) * 8;
          *(bf16x8*)&As[r][cc] = *(const bf16x8*)&W[(size_t)(o0 + r) * NC + k0 + cc];
          *(bf16x8*)&Bs[r][cc] = *(const bf16x8*)&Xb[(size_t)(n0 + r) * NC + k0 + cc]; }
        __syncthreads();
        bf16x8 a0 = *(const bf16x8*)&As[wm*32      + l16][g*8];
        bf16x8 a1 = *(const bf16x8*)&As[wm*32 + 16 + l16][g*8];
        bf16x8 b0 = *(const bf16x8*)&Bs[wn*32      + l16][g*8];
        bf16x8 b1 = *(const bf16x8*)&Bs[wn*32 + 16 + l16][g*8];
        acc[0][0] = MFMA16(a0, b0, acc[0][0]);
        acc[0][1] = MFMA16(a0, b1, acc[0][1]);
        acc[1][0] = MFMA16(a1, b0, acc[1][0]);
        acc[1][1] = MFMA16(a1, b1, acc[1][1]);
    }

#pragma unroll
    for (int sm = 0; sm < 2; ++sm)
#pragma unroll
    for (int sn = 0; sn < 2; ++sn) {
        const int col   = n0 + wn*32 + sn*16 + l16;
        const int obase = o0 + wm*32 + sm*16 + g*4;
        f32x4 v = acc[sm][sn];
        if (obase < 384) {
            const int hh = obase >> 5, d = obase & 31;
            bf16x4 o4;
#pragma unroll
            for (int r = 0; r < 4; ++r) o4[r] = (bf16)((v[r] + bq[obase + r]) * QSC);
            *(bf16x4*)&Qd[(((size_t)b*NH + hh)*NN + col)*HD + d] = o4;
        } else if (obase < 768) {
            const int oo = obase - 384; const int hh = oo >> 5, d = oo & 31;
            bf16x4 o4;
#pragma unroll
            for (int r = 0; r < 4; ++r) o4[r] = (bf16)(v[r] + bkv[oo + r]);
            *(bf16x4*)&Kd[(((size_t)b*NH + hh)*NN + col)*HD + d] = o4;
        } else {
            const int oo = obase - 768; const int hh = oo >> 5, d = oo & 31;
#pragma unroll
            for (int r = 0; r < 4; ++r)
                Vd[(((size_t)b*NH + hh)*HD + d + r)*NN + col] = (bf16)(v[r] + bkv[obase - 384 + r]);
        }
    }
}

// ---------------- fused flash attention (swapped QK^T, no online max) ----------------
// block = (q-tile 64, head, batch); 4 waves x 16 q-rows.
// S^T = mfma(K,Q): lane (g,l16) holds P[n=l16][m=16sc+4g+r] -> in-lane softmax row slice.
// bias idx computed arithmetically from hoisted terms; exp2 domain (Q,bias pre-scaled).
__global__ __launch_bounds__(256) void attn_kernel(
    const bf16* __restrict__ Qg, const bf16* __restrict__ Kg, const bf16* __restrict__ Vg,
    const float* __restrict__ bias_table, bf16* __restrict__ AOt)
{
    __shared__ bf16 biasc[NTBL];     // pre-scaled by log2e
    __shared__ bf16 Ks[64][32];      // [m][d]  stride 64B: conflict-free min
    __shared__ bf16 Vs[32][72];      // [d][m]  stride 144B: conflict-free min
    __shared__ bf16 Ps[4][16][72];   // per-wave P [n][m]

    const int t = threadIdx.x;
    const int w = t >> 6, lane = t & 63, g = lane >> 4, l16 = lane & 15;
    const int qt = blockIdx.x, h = blockIdx.y, b = blockIdx.z;

    for (int r = t; r < NTBL; r += 256)
        biasc[r] = (bf16)(bias_table[(size_t)r * NH + h] * LOG2E);

    const bf16* Qb = Qg + ((size_t)(b*NH + h)) * NN * HD;
    const bf16* Kb = Kg + ((size_t)(b*NH + h)) * NN * HD;
    const bf16* Vb = Vg + ((size_t)(b*NH + h)) * HD * NN;

    const int q0 = qt * 64;
    const int n_s = q0 + w*16 + l16;                 // this lane's softmax row
    const bf16x8 qfrag = *(const bf16x8*)&Qb[(size_t)n_s * HD + g*8];

    const int i1 = n_s >> 5;
    const int jb = (n_s & 31) + 31 - 4*g;            // j1 + 31 - 4g

    f32x4 oacc[2] = {};
    float l_run = 0.f;

    for (int m0 = 0; m0 < NN; m0 += 64) {
        __syncthreads();
        { const int mm = t >> 2, dg = (t & 3) * 8;
          *(bf16x8*)&Ks[mm][dg] = *(const bf16x8*)&Kb[(size_t)(m0 + mm)*HD + dg]; }
        { const int d = t >> 3, mg = (t & 7) * 8;
          *(bf16x8*)&Vs[d][mg] = *(const bf16x8*)&Vb[(size_t)d*NN + m0 + mg]; }
        __syncthreads();

        const int ibx = (i1 - (m0 >> 5) + 31) * 63;
        float p[4][4];
        float lsum = 0.f;
#pragma unroll
        for (int sc = 0; sc < 4; ++sc) {
            bf16x8 kf = *(const bf16x8*)&Ks[sc*16 + l16][g*8];
            f32x4 z = {0.f, 0.f, 0.f, 0.f};
            z = MFMA16(kf, qfrag, z);                 // S^T: row m, col n
            const int cb = ibx - (sc >> 1)*63 + jb - 16*(sc & 1);
#pragma unroll
            for (int r = 0; r < 4; ++r) {
                float sv = z[r] + (float)biasc[cb - r];
                float pv = exp2f(sv);
                p[sc][r] = pv;
                lsum += pv;
            }
        }
        lsum += __shfl_xor(lsum, 16);
        lsum += __shfl_xor(lsum, 32);
        l_run += lsum;

#pragma unroll
        for (int sc = 0; sc < 4; ++sc)
#pragma unroll
            for (int u = 0; u < 2; ++u) {
                bf16x2 pr; pr[0] = (bf16)p[sc][2*u]; pr[1] = (bf16)p[sc][2*u + 1];
                *(bf16x2*)&Ps[w][l16][sc*16 + g*4 + 2*u] = pr;
            }

        // same-wave LDS write->read; compiler inserts lgkmcnt wait
#pragma unroll
        for (int kc = 0; kc < 2; ++kc) {
            bf16x8 pf = *(const bf16x8*)&Ps[w][l16][kc*32 + g*8];
#pragma unroll
            for (int ds = 0; ds < 2; ++ds) {
                bf16x8 vf = *(const bf16x8*)&Vs[ds*16 + l16][kc*32 + g*8];
                oacc[ds] = MFMA16(pf, vf, oacc[ds]);
            }
        }
    }

    // output rows n = q0+16w+4g+r; their l sits at lane l16' = 4g+r (same g-group)
    const int sbase = (lane & 48) | ((lane >> 2) & 12);
    float rin[4];
#pragma unroll
    for (int r = 0; r < 4; ++r) rin[r] = 1.0f / __shfl(l_run, sbase + r);

    const int nrow = q0 + w*16 + g*4;
#pragma unroll
    for (int ds = 0; ds < 2; ++ds) {
        const int c = h*HD + ds*16 + l16;
#pragma unroll
        for (int r = 0; r < 4; ++r)
            AOt[((size_t)b*NN + nrow + r) * NC + c] = (bf16)(oacc[ds][r] * rin[r]);
    }
}

// ---------------- output projection GEMM ----------------
// out[b,o,n] = sum_m Wp[o,m] * AOt[b,n,m] + bproj[o]   (fp32 out)
__global__ __launch_bounds__(256) void proj_gemm_kernel(
    const bf16* __restrict__ W, const bf16* __restrict__ AOt,
    const float* __restrict__ bproj, float* __restrict__ out)
{
    __shared__ bf16 As[64][40];
    __shared__ bf16 Bs[64][40];
    const int t = threadIdx.x;
    const int w = t >> 6, lane = t & 63, g = lane >> 4, l16 = lane & 15;
    const int wm = w >> 1, wn = w & 1;
    const int n0g = blockIdx.x * 64;
    const int b = n0g >> 10, n0 = n0g & 1023;
    const int o0 = blockIdx.y * 64;
    const bf16* Ab = AOt + (size_t)b * NN * NC;

    f32x4 acc[2][2] = {};

    for (int k0 = 0; k0 < NC; k0 += 32) {
        __syncthreads();
        { const int r = t >> 2, cc = (t & 3) * 8;
          *(bf16x8*)&As[r][cc] = *(const bf16x8*)&W[(size_t)(o0 + r) * NC + k0 + cc];
          *(bf16x8*)&Bs[r][cc] = *(const bf16x8*)&Ab[(size_t)(n0 + r) * NC + k0 + cc]; }
        __syncthreads();
        bf16x8 a0 = *(const bf16x8*)&As[wm*32      + l16][g*8];
        bf16x8 a1 = *(const bf16x8*)&As[wm*32 + 16 + l16][g*8];
        bf16x8 b0 = *(const bf16x8*)&Bs[wn*32      + l16][g*8];
        bf16x8 b1 = *(const bf16x8*)&Bs[wn*32 + 16 + l16][g*8];
        acc[0][0] = MFMA16(a0, b0, acc[0][0]);
        acc[0][1] = MFMA16(a0, b1, acc[0][1]);
        acc[1][0] = MFMA16(a1, b0, acc[1][0]);
        acc[1][1] = MFMA16(a1, b1, acc[1][1]);
    }

#pragma unroll
    for (int sm = 0; sm < 2; ++sm)
#pragma unroll
    for (int sn = 0; sn < 2; ++sn) {
        const int col   = n0 + wn*32 + sn*16 + l16;
        const int obase = o0 + wm*32 + sm*16 + g*4;
        f32x4 v = acc[sm][sn];
#pragma unroll
        for (int r = 0; r < 4; ++r)
            out[((size_t)b*NC + obase + r)*NN + col] = v[r] + bproj[obase + r];
    }
}

extern "C" void kernel_launch(void* const* d_in, const int* in_sizes, int n_in,
                              void* d_out, int out_size, void* d_ws, size_t ws_size,
                              hipStream_t stream)
{
    const float* x          = (const float*)d_in[0];
    const float* wq         = (const float*)d_in[1];
    const float* bq         = (const float*)d_in[2];
    const float* wkv        = (const float*)d_in[3];
    const float* bkv        = (const float*)d_in[4];
    const float* wproj      = (const float*)d_in[5];
    const float* bproj      = (const float*)d_in[6];
    const float* bias_table = (const float*)d_in[7];
    // d_in[8] = rel_index: unused (bias index computed arithmetically in-kernel)
    float* out = (float*)d_out;

    bf16* wsb  = (bf16*)d_ws;
    bf16* Xt   = wsb + XT_OFF;
    bf16* Wqkv = wsb + WQKV_OFF;
    bf16* Wp   = wsb + WP_OFF;
    bf16* Qd   = wsb + Q_OFF;
    bf16* Kd   = wsb + K_OFF;
    bf16* Vd   = wsb + V_OFF;
    bf16* AOt  = wsb + AO_OFF;

    cast_xt_kernel<<<dim3(NB * 96), 256, 0, stream>>>(x, Xt);
    cast_w_kernel<<<dim3((unsigned)((WQKV_N + WP_N)/4/256)), 256, 0, stream>>>(wq, wkv, wproj, Wqkv, Wp);
    qkv_gemm_kernel<<<dim3(128, 18), 256, 0, stream>>>(Wqkv, Xt, bq, bkv, Qd, Kd, Vd);
    attn_kernel<<<dim3(16, 12, 8), 256, 0, stream>>>(Qd, Kd, Vd, bias_table, AOt);
    proj_gemm_kernel<<<dim3(128, 6), 256, 0, stream>>>(Wp, AOt, bproj, out);
}

// Round 4
// 84.921 us; speedup vs baseline: 1.7688x; 1.4998x over previous
//
#include <hip/hip_runtime.h>

typedef __bf16 bf16;
typedef __bf16 bf16x8 __attribute__((ext_vector_type(8)));
typedef __bf16 bf16x4 __attribute__((ext_vector_type(4)));
typedef float  f32x4  __attribute__((ext_vector_type(4)));

static constexpr int NB = 8;      // batch
static constexpr int NH = 12;     // heads
static constexpr int HD = 32;     // head dim
static constexpr int NN = 1024;   // tokens (32x32)
static constexpr int NC = 384;    // channels
static constexpr int NTBL = 3969; // (2*32-1)^2

static constexpr float LOG2E = 1.4426950408889634f;
static constexpr float QSC   = (float)(0.17677669529663687 * 1.4426950408889634); // scale*log2e

static constexpr size_t XT_N   = (size_t)NB*NN*NC;    // x transposed [b][n][c] bf16
static constexpr size_t WQKV_N = (size_t)3*NC*NC;
static constexpr size_t WP_N   = (size_t)NC*NC;
static constexpr size_t QKV_N  = (size_t)NB*NH*NN*HD;

static constexpr size_t XT_OFF   = 0;
static constexpr size_t WQKV_OFF = XT_OFF + XT_N;
static constexpr size_t WP_OFF   = WQKV_OFF + WQKV_N;
static constexpr size_t Q_OFF    = WP_OFF + WP_N;
static constexpr size_t K_OFF    = Q_OFF + QKV_N;
static constexpr size_t V_OFF    = K_OFF + QKV_N;
static constexpr size_t AO_OFF   = V_OFF + QKV_N;     // [b][n][c] bf16

#define MFMA16(a,b,c) __builtin_amdgcn_mfma_f32_16x16x32_bf16(a,b,c,0,0,0)

// ---------------- cast + transpose x: [b][c][n] f32 -> [b][n][c] bf16 ----------------
__global__ __launch_bounds__(256) void cast_xt_kernel(const float* __restrict__ x,
                                                      bf16* __restrict__ xt)
{
    __shared__ bf16 T[64][68];
    const int t = threadIdx.x;
    const int bid = blockIdx.x;            // b*96 + ct*16 + nt
    const int b = bid / 96, rem = bid % 96, ct = rem >> 4, nt = rem & 15;
    const int c0 = ct * 64, n0 = nt * 64;
    const float* Xb = x + (size_t)b * NC * NN;
    const int nl = t & 63, c4 = (t >> 6) * 4;
#pragma unroll
    for (int i = 0; i < 4; ++i) {
        const int c = c4 + i * 16;
        bf16x4 v;
#pragma unroll
        for (int j = 0; j < 4; ++j)
            v[j] = (bf16)Xb[(size_t)(c0 + c + j) * NN + n0 + nl];  // coalesced over nl
        *(bf16x4*)&T[nl][c] = v;
    }
    __syncthreads();
    const int n = t >> 2;
#pragma unroll
    for (int i = 0; i < 2; ++i) {
        const int cg = (t & 3) * 8 + i * 32;
        bf16x4 a = *(const bf16x4*)&T[n][cg];
        bf16x4 bv = *(const bf16x4*)&T[n][cg + 4];
        bf16x8 vv = __builtin_shufflevector(a, bv, 0, 1, 2, 3, 4, 5, 6, 7);
        *(bf16x8*)&xt[((size_t)b * NN + n0 + n) * NC + c0 + cg] = vv;
    }
}

// ---------------- cast weights ----------------
__global__ __launch_bounds__(256) void cast_w_kernel(const float* __restrict__ wq,
                                                     const float* __restrict__ wkv,
                                                     const float* __restrict__ wproj,
                                                     bf16* __restrict__ wqkv,
                                                     bf16* __restrict__ wp)
{
    const size_t i = ((size_t)blockIdx.x * 256 + threadIdx.x) * 4;
    if (i >= WQKV_N + WP_N) return;
    const float* src; bf16* dst;
    if (i < (size_t)NC*NC)      { src = wq + i;                     dst = wqkv + i; }
    else if (i < WQKV_N)        { src = wkv + (i - (size_t)NC*NC);  dst = wqkv + i; }
    else                        { src = wproj + (i - WQKV_N);       dst = wp + (i - WQKV_N); }
    float4 v = *(const float4*)src;
    bf16x4 o; o[0] = (bf16)v.x; o[1] = (bf16)v.y; o[2] = (bf16)v.z; o[3] = (bf16)v.w;
    *(bf16x4*)dst = o;
}

// ---------------- QKV projection GEMM ----------------
__global__ __launch_bounds__(256) void qkv_gemm_kernel(
    const bf16* __restrict__ W, const bf16* __restrict__ Xt,
    const float* __restrict__ bq, const float* __restrict__ bkv,
    bf16* __restrict__ Qd, bf16* __restrict__ Kd, bf16* __restrict__ Vd)
{
    __shared__ bf16 As[64][40];   // [o][c]
    __shared__ bf16 Bs[64][40];   // [n][c]
    const int t = threadIdx.x;
    const int w = t >> 6, lane = t & 63, g = lane >> 4, l16 = lane & 15;
    const int wm = w >> 1, wn = w & 1;
    const int n0g = blockIdx.x * 64;
    const int b = n0g >> 10, n0 = n0g & 1023;
    const int o0 = blockIdx.y * 64;
    const bf16* Xb = Xt + (size_t)b * NN * NC;

    f32x4 acc[2][2] = {};

    for (int k0 = 0; k0 < NC; k0 += 32) {
        __syncthreads();
        { const int r = t >> 2, cc = (t & 3) * 8;
          *(bf16x8*)&As[r][cc] = *(const bf16x8*)&W[(size_t)(o0 + r) * NC + k0 + cc];
          *(bf16x8*)&Bs[r][cc] = *(const bf16x8*)&Xb[(size_t)(n0 + r) * NC + k0 + cc]; }
        __syncthreads();
        bf16x8 a0 = *(const bf16x8*)&As[wm*32      + l16][g*8];
        bf16x8 a1 = *(const bf16x8*)&As[wm*32 + 16 + l16][g*8];
        bf16x8 b0 = *(const bf16x8*)&Bs[wn*32      + l16][g*8];
        bf16x8 b1 = *(const bf16x8*)&Bs[wn*32 + 16 + l16][g*8];
        acc[0][0] = MFMA16(a0, b0, acc[0][0]);
        acc[0][1] = MFMA16(a0, b1, acc[0][1]);
        acc[1][0] = MFMA16(a1, b0, acc[1][0]);
        acc[1][1] = MFMA16(a1, b1, acc[1][1]);
    }

#pragma unroll
    for (int sm = 0; sm < 2; ++sm)
#pragma unroll
    for (int sn = 0; sn < 2; ++sn) {
        const int col   = n0 + wn*32 + sn*16 + l16;
        const int obase = o0 + wm*32 + sm*16 + g*4;
        f32x4 v = acc[sm][sn];
        if (obase < 384) {
            const int hh = obase >> 5, d = obase & 31;
            bf16x4 o4;
#pragma unroll
            for (int r = 0; r < 4; ++r) o4[r] = (bf16)((v[r] + bq[obase + r]) * QSC);
            *(bf16x4*)&Qd[(((size_t)b*NH + hh)*NN + col)*HD + d] = o4;
        } else if (obase < 768) {
            const int oo = obase - 384; const int hh = oo >> 5, d = oo & 31;
            bf16x4 o4;
#pragma unroll
            for (int r = 0; r < 4; ++r) o4[r] = (bf16)(v[r] + bkv[oo + r]);
            *(bf16x4*)&Kd[(((size_t)b*NH + hh)*NN + col)*HD + d] = o4;
        } else {
            const int oo = obase - 768; const int hh = oo >> 5, d = oo & 31;
#pragma unroll
            for (int r = 0; r < 4; ++r)
                Vd[(((size_t)b*NH + hh)*HD + d + r)*NN + col] = (bf16)(v[r] + bkv[obase - 384 + r]);
        }
    }
}

// ---------------- fused flash attention ----------------
// 512 threads (8 waves), QBLK=128, KVBLK=64. Conservative r2-proven schedule:
// B0 -> ds_write tile -> B1 -> issue next loads (T14) -> compute. Single-buffered.
// Swapped QK^T (lane holds P-row slice in registers); PV uses a relabeled
// contraction index so P NEVER goes through LDS (A = in-lane register pack,
// V LDS columns permuted to match). Bias via packed pair-table (1 b32 read
// yields bias[di0] and bias[di0-1]); no online max (exp2-domain safe).
__global__ __launch_bounds__(512) void attn_kernel(
    const bf16* __restrict__ Qg, const bf16* __restrict__ Kg, const bf16* __restrict__ Vg,
    const float* __restrict__ bias_table, bf16* __restrict__ AOt)
{
    __shared__ unsigned short bsc[NTBL];     // bf16 bits, pre-scaled by log2e
    __shared__ unsigned int pairTu[63][63];  // [dj][dip]: lo16=bias[dip-30], hi16=bias[dip-31]
    __shared__ bf16 Ks[64][40];              // [m][d]   stride 80B (odd x16B)
    __shared__ bf16 Vs[32][72];              // [d][m]   stride 144B (odd x16B)

    const int t = threadIdx.x;
    const int w = t >> 6, lane = t & 63, g = lane >> 4, l16 = lane & 15;
    const int qt = blockIdx.x, h = blockIdx.y, b = blockIdx.z;

    const bf16* Qb = Qg + ((size_t)(b*NH + h)) * NN * HD;
    const bf16* Kb = Kg + ((size_t)(b*NH + h)) * NN * HD;
    const bf16* Vb = Vg + ((size_t)(b*NH + h)) * HD * NN;

    // staging roles (wave-uniform): waves 0-3 -> K tile, waves 4-7 -> V tile
    const bool isK = (t < 256);
    const int kr = t >> 2, kc2 = (t & 3) * 8;
    const int tv = t & 255, vd = tv >> 3, vm = (tv & 7) * 8;

    // issue tile-0 loads first (latency hides under bias staging)
    bf16x8 sreg = isK ? *(const bf16x8*)&Kb[(size_t)kr * HD + kc2]
                      : *(const bf16x8*)&Vb[(size_t)vd * NN + vm];

    for (int r = t; r < NTBL; r += 512) {
        bf16 v = (bf16)(bias_table[(size_t)r * NH + h] * LOG2E);
        bsc[r] = __builtin_bit_cast(unsigned short, v);
    }
    __syncthreads();
    for (int idx = t; idx < 63 * 62; idx += 512) {
        const int dj = idx / 62, dip = idx % 62;
        pairTu[dj][dip] = (unsigned)bsc[(dip + 1) * 63 + dj]
                        | ((unsigned)bsc[dip * 63 + dj] << 16);
    }
    // pairTu reads begin after the loop's first two barriers -> visible

    const int q0 = qt * 128;
    const int n_s = q0 + w*16 + l16;                 // this lane's softmax row
    const bf16x8 qfrag = *(const bf16x8*)&Qb[(size_t)n_s * HD + g*8];

    const int i1w = (q0 >> 5) + (w >> 1);            // wave-uniform i1
    const int j1 = ((w & 1) << 4) | l16;
    const int jA63 = (j1 + 31 - 4*g) * 63;           // row base for sc-even (minus 63r)

    f32x4 oacc[2] = {};
    float l_run = 0.f;

    for (int it = 0; it < 16; ++it) {
        __syncthreads();                              // B0: all reads of prev tile done
        if (isK) *(bf16x8*)&Ks[kr][kc2] = sreg;
        else     *(bf16x8*)&Vs[vd][vm] = sreg;
        __syncthreads();                              // B1: tile visible
        if (it < 15) {                                // T14: issue next tile early
            const int m1 = (it + 1) * 64;
            sreg = isK ? *(const bf16x8*)&Kb[(size_t)(m1 + kr) * HD + kc2]
                       : *(const bf16x8*)&Vb[(size_t)vd * NN + m1 + vm];
        }

        const int dip = i1w - 2*it + 30;              // in [0,62)
        const unsigned* pAp = &pairTu[0][0] + jA63 + dip;

        f32x4 z[4];
#pragma unroll
        for (int sc = 0; sc < 4; ++sc) {
            bf16x8 kf = *(const bf16x8*)&Ks[sc*16 + l16][g*8];
            f32x4 zz = {0.f, 0.f, 0.f, 0.f};
            z[sc] = MFMA16(kf, qfrag, zz);            // S^T: m-row, n-col
        }

        float p[4][4];
        float lsum = 0.f;
#pragma unroll
        for (int r = 0; r < 4; ++r) {
            const unsigned prA = pAp[-63 * r];            // sc even: dj = j1+31-4g-r
            const unsigned prB = pAp[-63 * r - 1008];     // sc odd:  dj -= 16 rows
            float p0 = exp2f(z[0][r] + __uint_as_float(prA << 16));
            float p2 = exp2f(z[2][r] + __uint_as_float(prA & 0xFFFF0000u));
            float p1 = exp2f(z[1][r] + __uint_as_float(prB << 16));
            float p3 = exp2f(z[3][r] + __uint_as_float(prB & 0xFFFF0000u));
            p[0][r] = p0; p[1][r] = p1; p[2][r] = p2; p[3][r] = p3;
            lsum += (p0 + p1) + (p2 + p3);
        }
        l_run += lsum;                                // cross-lane reduce deferred

        // PV with relabeled contraction: slot k=8g+4sh+r <-> m=32kc+16sh+4g+r.
        // A = in-register P pack; B = Vs cols {32kc+4g..+3, 32kc+16+4g..+3}.
#pragma unroll
        for (int kc = 0; kc < 2; ++kc) {
            bf16x8 pa;
#pragma unroll
            for (int r = 0; r < 4; ++r) {
                pa[r]     = (bf16)p[2*kc][r];
                pa[4 + r] = (bf16)p[2*kc + 1][r];
            }
#pragma unroll
            for (int ds = 0; ds < 2; ++ds) {
                const bf16* vrow = &Vs[ds*16 + l16][kc*32 + 4*g];
                bf16x4 lo = *(const bf16x4*)vrow;
                bf16x4 hi = *(const bf16x4*)(vrow + 16);
                bf16x8 vf = __builtin_shufflevector(lo, hi, 0, 1, 2, 3, 4, 5, 6, 7);
                oacc[ds] = MFMA16(pa, vf, oacc[ds]);
            }
        }
    }

    // row-sum: lanes sharing l16 (4 g-groups) hold complementary m-slices
    l_run += __shfl_xor(l_run, 16);
    l_run += __shfl_xor(l_run, 32);
    const int sbase = (lane & 48) | ((lane >> 2) & 12);
    float rin[4];
#pragma unroll
    for (int r = 0; r < 4; ++r) rin[r] = 1.0f / __shfl(l_run, sbase + r);

    const int nrow = q0 + w*16 + g*4;
#pragma unroll
    for (int ds = 0; ds < 2; ++ds) {
        const int c = h*HD + ds*16 + l16;
#pragma unroll
        for (int r = 0; r < 4; ++r)
            AOt[((size_t)b*NN + nrow + r) * NC + c] = (bf16)(oacc[ds][r] * rin[r]);
    }
}

// ---------------- output projection GEMM ----------------
__global__ __launch_bounds__(256) void proj_gemm_kernel(
    const bf16* __restrict__ W, const bf16* __restrict__ AOt,
    const float* __restrict__ bproj, float* __restrict__ out)
{
    __shared__ bf16 As[64][40];
    __shared__ bf16 Bs[64][40];
    const int t = threadIdx.x;
    const int w = t >> 6, lane = t & 63, g = lane >> 4, l16 = lane & 15;
    const int wm = w >> 1, wn = w & 1;
    const int n0g = blockIdx.x * 64;
    const int b = n0g >> 10, n0 = n0g & 1023;
    const int o0 = blockIdx.y * 64;
    const bf16* Ab = AOt + (size_t)b * NN * NC;

    f32x4 acc[2][2] = {};

    for (int k0 = 0; k0 < NC; k0 += 32) {
        __syncthreads();
        { const int r = t >> 2, cc = (t & 3) * 8;
          *(bf16x8*)&As[r][cc] = *(const bf16x8*)&W[(size_t)(o0 + r) * NC + k0 + cc];
          *(bf16x8*)&Bs[r][cc] = *(const bf16x8*)&Ab[(size_t)(n0 + r) * NC + k0 + cc]; }
        __syncthreads();
        bf16x8 a0 = *(const bf16x8*)&As[wm*32      + l16][g*8];
        bf16x8 a1 = *(const bf16x8*)&As[wm*32 + 16 + l16][g*8];
        bf16x8 b0 = *(const bf16x8*)&Bs[wn*32      + l16][g*8];
        bf16x8 b1 = *(const bf16x8*)&Bs[wn*32 + 16 + l16][g*8];
        acc[0][0] = MFMA16(a0, b0, acc[0][0]);
        acc[0][1] = MFMA16(a0, b1, acc[0][1]);
        acc[1][0] = MFMA16(a1, b0, acc[1][0]);
        acc[1][1] = MFMA16(a1, b1, acc[1][1]);
    }

#pragma unroll
    for (int sm = 0; sm < 2; ++sm)
#pragma unroll
    for (int sn = 0; sn < 2; ++sn) {
        const int col   = n0 + wn*32 + sn*16 + l16;
        const int obase = o0 + wm*32 + sm*16 + g*4;
        f32x4 v = acc[sm][sn];
#pragma unroll
        for (int r = 0; r < 4; ++r)
            out[((size_t)b*NC + obase + r)*NN + col] = v[r] + bproj[obase + r];
    }
}

extern "C" void kernel_launch(void* const* d_in, const int* in_sizes, int n_in,
                              void* d_out, int out_size, void* d_ws, size_t ws_size,
                              hipStream_t stream)
{
    const float* x          = (const float*)d_in[0];
    const float* wq         = (const float*)d_in[1];
    const float* bq         = (const float*)d_in[2];
    const float* wkv        = (const float*)d_in[3];
    const float* bkv        = (const float*)d_in[4];
    const float* wproj      = (const float*)d_in[5];
    const float* bproj      = (const float*)d_in[6];
    const float* bias_table = (const float*)d_in[7];
    // d_in[8] = rel_index: unused (bias index computed arithmetically in-kernel)
    float* out = (float*)d_out;

    bf16* wsb  = (bf16*)d_ws;
    bf16* Xt   = wsb + XT_OFF;
    bf16* Wqkv = wsb + WQKV_OFF;
    bf16* Wp   = wsb + WP_OFF;
    bf16* Qd   = wsb + Q_OFF;
    bf16* Kd   = wsb + K_OFF;
    bf16* Vd   = wsb + V_OFF;
    bf16* AOt  = wsb + AO_OFF;

    cast_xt_kernel<<<dim3(NB * 96), 256, 0, stream>>>(x, Xt);
    cast_w_kernel<<<dim3((unsigned)((WQKV_N + WP_N)/4/256)), 256, 0, stream>>>(wq, wkv, wproj, Wqkv, Wp);
    qkv_gemm_kernel<<<dim3(128, 18), 256, 0, stream>>>(Wqkv, Xt, bq, bkv, Qd, Kd, Vd);
    attn_kernel<<<dim3(8, 12, 8), 512, 0, stream>>>(Qd, Kd, Vd, bias_table, AOt);
    proj_gemm_kernel<<<dim3(128, 6), 256, 0, stream>>>(Wp, AOt, bproj, out);
}

// Round 5
// 80.541 us; speedup vs baseline: 1.8650x; 1.0544x over previous
//
#include <hip/hip_runtime.h>

typedef __bf16 bf16;
typedef __bf16 bf16x8 __attribute__((ext_vector_type(8)));
typedef __bf16 bf16x4 __attribute__((ext_vector_type(4)));
typedef float  f32x4  __attribute__((ext_vector_type(4)));

static constexpr int NB = 8;      // batch
static constexpr int NH = 12;     // heads
static constexpr int HD = 32;     // head dim
static constexpr int NN = 1024;   // tokens (32x32)
static constexpr int NC = 384;    // channels
static constexpr int NTBL = 3969; // (2*32-1)^2

static constexpr float LOG2E = 1.4426950408889634f;
static constexpr float QSC   = (float)(0.17677669529663687 * 1.4426950408889634); // scale*log2e

static constexpr size_t XT_N   = (size_t)NB*NN*NC;    // x transposed [b][n][c] bf16
static constexpr size_t WQKV_N = (size_t)3*NC*NC;
static constexpr size_t WP_N   = (size_t)NC*NC;
static constexpr size_t QKV_N  = (size_t)NB*NH*NN*HD;

static constexpr size_t XT_OFF   = 0;
static constexpr size_t WQKV_OFF = XT_OFF + XT_N;
static constexpr size_t WP_OFF   = WQKV_OFF + WQKV_N;
static constexpr size_t Q_OFF    = WP_OFF + WP_N;
static constexpr size_t K_OFF    = Q_OFF + QKV_N;
static constexpr size_t V_OFF    = K_OFF + QKV_N;
static constexpr size_t AO_OFF   = V_OFF + QKV_N;     // [b][n][c] bf16

#define MFMA16(a,b,c) __builtin_amdgcn_mfma_f32_16x16x32_bf16(a,b,c,0,0,0)

// ---------------- cast + transpose x: [b][c][n] f32 -> [b][n][c] bf16 ----------------
__global__ __launch_bounds__(256) void cast_xt_kernel(const float* __restrict__ x,
                                                      bf16* __restrict__ xt)
{
    __shared__ bf16 T[64][68];
    const int t = threadIdx.x;
    const int bid = blockIdx.x;            // b*96 + ct*16 + nt
    const int b = bid / 96, rem = bid % 96, ct = rem >> 4, nt = rem & 15;
    const int c0 = ct * 64, n0 = nt * 64;
    const float* Xb = x + (size_t)b * NC * NN;
    const int nl = t & 63, c4 = (t >> 6) * 4;
#pragma unroll
    for (int i = 0; i < 4; ++i) {
        const int c = c4 + i * 16;
        bf16x4 v;
#pragma unroll
        for (int j = 0; j < 4; ++j)
            v[j] = (bf16)Xb[(size_t)(c0 + c + j) * NN + n0 + nl];  // coalesced over nl
        *(bf16x4*)&T[nl][c] = v;
    }
    __syncthreads();
    const int n = t >> 2;
#pragma unroll
    for (int i = 0; i < 2; ++i) {
        const int cg = (t & 3) * 8 + i * 32;
        bf16x4 a = *(const bf16x4*)&T[n][cg];
        bf16x4 bv = *(const bf16x4*)&T[n][cg + 4];
        bf16x8 vv = __builtin_shufflevector(a, bv, 0, 1, 2, 3, 4, 5, 6, 7);
        *(bf16x8*)&xt[((size_t)b * NN + n0 + n) * NC + c0 + cg] = vv;
    }
}

// ---------------- cast weights ----------------
__global__ __launch_bounds__(256) void cast_w_kernel(const float* __restrict__ wq,
                                                     const float* __restrict__ wkv,
                                                     const float* __restrict__ wproj,
                                                     bf16* __restrict__ wqkv,
                                                     bf16* __restrict__ wp)
{
    const size_t i = ((size_t)blockIdx.x * 256 + threadIdx.x) * 4;
    if (i >= WQKV_N + WP_N) return;
    const float* src; bf16* dst;
    if (i < (size_t)NC*NC)      { src = wq + i;                     dst = wqkv + i; }
    else if (i < WQKV_N)        { src = wkv + (i - (size_t)NC*NC);  dst = wqkv + i; }
    else                        { src = wproj + (i - WQKV_N);       dst = wp + (i - WQKV_N); }
    float4 v = *(const float4*)src;
    bf16x4 o; o[0] = (bf16)v.x; o[1] = (bf16)v.y; o[2] = (bf16)v.z; o[3] = (bf16)v.w;
    *(bf16x4*)dst = o;
}

// ---------------- QKV projection GEMM (64x128 tile, reg-prefetch) ----------------
__global__ __launch_bounds__(256) void qkv_gemm_kernel(
    const bf16* __restrict__ W, const bf16* __restrict__ Xt,
    const float* __restrict__ bq, const float* __restrict__ bkv,
    bf16* __restrict__ Qd, bf16* __restrict__ Kd, bf16* __restrict__ Vd)
{
    __shared__ bf16 As[64][40];    // [o][c]
    __shared__ bf16 Bs[128][40];   // [n][c]
    const int t = threadIdx.x;
    const int w = t >> 6, lane = t & 63, g = lane >> 4, l16 = lane & 15;
    const int wm = w >> 1, wn = w & 1;
    const int n0g = blockIdx.x * 128;
    const int b = n0g >> 10, n0 = n0g & 1023;
    const int o0 = blockIdx.y * 64;
    const bf16* Xb = Xt + (size_t)b * NN * NC;

    const int ar = t >> 2, ac = (t & 3) * 8;
    const int br0 = t >> 1;        // unused; staging via slot loop below

    f32x4 acc[2][4] = {};

    // prologue: load k-tile 0 into regs
    bf16x8 aw = *(const bf16x8*)&W[(size_t)(o0 + ar) * NC + ac];
    bf16x8 bw[2];
#pragma unroll
    for (int i = 0; i < 2; ++i) {
        const int s = t + i * 256, r = s >> 2, cc = (s & 3) * 8;
        bw[i] = *(const bf16x8*)&Xb[(size_t)(n0 + r) * NC + cc];
    }
    (void)br0;

    for (int k0 = 0; k0 < NC; k0 += 32) {
        __syncthreads();
        *(bf16x8*)&As[ar][ac] = aw;
#pragma unroll
        for (int i = 0; i < 2; ++i) {
            const int s = t + i * 256, r = s >> 2, cc = (s & 3) * 8;
            *(bf16x8*)&Bs[r][cc] = bw[i];
        }
        __syncthreads();
        if (k0 + 32 < NC) {        // early-issue next k-tile (hides under MFMA)
            aw = *(const bf16x8*)&W[(size_t)(o0 + ar) * NC + k0 + 32 + ac];
#pragma unroll
            for (int i = 0; i < 2; ++i) {
                const int s = t + i * 256, r = s >> 2, cc = (s & 3) * 8;
                bw[i] = *(const bf16x8*)&Xb[(size_t)(n0 + r) * NC + k0 + 32 + cc];
            }
        }
        bf16x8 a0 = *(const bf16x8*)&As[wm*32      + l16][g*8];
        bf16x8 a1 = *(const bf16x8*)&As[wm*32 + 16 + l16][g*8];
#pragma unroll
        for (int sn = 0; sn < 4; ++sn) {
            bf16x8 bf = *(const bf16x8*)&Bs[wn*64 + sn*16 + l16][g*8];
            acc[0][sn] = MFMA16(a0, bf, acc[0][sn]);
            acc[1][sn] = MFMA16(a1, bf, acc[1][sn]);
        }
    }

#pragma unroll
    for (int sm = 0; sm < 2; ++sm)
#pragma unroll
    for (int sn = 0; sn < 4; ++sn) {
        const int col   = n0 + wn*64 + sn*16 + l16;
        const int obase = o0 + wm*32 + sm*16 + g*4;
        f32x4 v = acc[sm][sn];
        if (obase < 384) {
            const int hh = obase >> 5, d = obase & 31;
            bf16x4 o4;
#pragma unroll
            for (int r = 0; r < 4; ++r) o4[r] = (bf16)((v[r] + bq[obase + r]) * QSC);
            *(bf16x4*)&Qd[(((size_t)b*NH + hh)*NN + col)*HD + d] = o4;
        } else if (obase < 768) {
            const int oo = obase - 384; const int hh = oo >> 5, d = oo & 31;
            bf16x4 o4;
#pragma unroll
            for (int r = 0; r < 4; ++r) o4[r] = (bf16)(v[r] + bkv[oo + r]);
            *(bf16x4*)&Kd[(((size_t)b*NH + hh)*NN + col)*HD + d] = o4;
        } else {
            const int oo = obase - 768; const int hh = oo >> 5, d = oo & 31;
#pragma unroll
            for (int r = 0; r < 4; ++r)
                Vd[(((size_t)b*NH + hh)*HD + d + r)*NN + col] = (bf16)(v[r] + bkv[obase - 384 + r]);
        }
    }
}

// ---------------- fused flash attention ----------------
// 512 threads (8 waves), QBLK=128, 128 keys per barrier phase (2 x 64 sub-tiles).
// Schedule per phase (r4-proven): B0 -> ds_write staged regs -> B1 -> issue
// next phase's loads -> compute sub0, sub1. Single-buffered.
// Swapped QK^T (lane holds P-row slice in registers); PV uses relabeled
// contraction so P never touches LDS. Bias via packed pair-table.
__global__ __launch_bounds__(512) void attn_kernel(
    const bf16* __restrict__ Qg, const bf16* __restrict__ Kg, const bf16* __restrict__ Vg,
    const float* __restrict__ bias_table, bf16* __restrict__ AOt)
{
    __shared__ unsigned short bsc[NTBL];     // bf16 bits, pre-scaled by log2e
    __shared__ unsigned int pairTu[63][63];  // [dj][dip]: lo16=bias[dip-30], hi16=bias[dip-31]
    __shared__ bf16 Ks[128][40];             // [m][d]   stride 80B (odd x16B)
    __shared__ bf16 Vs0[32][72];             // [d][m]   m 0..63 of phase
    __shared__ bf16 Vs1[32][72];             // [d][m]   m 64..127 of phase

    const int t = threadIdx.x;
    const int w = t >> 6, lane = t & 63, g = lane >> 4, l16 = lane & 15;
    const int qt = blockIdx.x, h = blockIdx.y, b = blockIdx.z;

    const bf16* Qb = Qg + ((size_t)(b*NH + h)) * NN * HD;
    const bf16* Kb = Kg + ((size_t)(b*NH + h)) * NN * HD;
    const bf16* Vb = Vg + ((size_t)(b*NH + h)) * HD * NN;

    // staging slots (all 512 threads stage one K-vec and one V-vec per phase)
    const int kr = t >> 2, kc2 = (t & 3) * 8;         // K: 128 rows x 4 col-chunks
    const int vd = t >> 4, vmi = (t & 15) * 8;        // V: 32 d x 16 m-chunks (0..120)
    bf16* vdst = (vmi < 64) ? &Vs0[vd][vmi] : &Vs1[vd][vmi - 64];

    // issue phase-0 loads first (latency hides under bias staging)
    bf16x8 sregK = *(const bf16x8*)&Kb[(size_t)kr * HD + kc2];
    bf16x8 sregV = *(const bf16x8*)&Vb[(size_t)vd * NN + vmi];

    for (int r = t; r < NTBL; r += 512) {
        bf16 v = (bf16)(bias_table[(size_t)r * NH + h] * LOG2E);
        bsc[r] = __builtin_bit_cast(unsigned short, v);
    }
    __syncthreads();
    for (int idx = t; idx < 63 * 62; idx += 512) {
        const int dj = idx / 62, dip = idx % 62;
        pairTu[dj][dip] = (unsigned)bsc[(dip + 1) * 63 + dj]
                        | ((unsigned)bsc[dip * 63 + dj] << 16);
    }
    // pairTu reads begin after the loop's first two barriers -> visible

    const int q0 = qt * 128;
    const int n_s = q0 + w*16 + l16;                 // this lane's softmax row
    const bf16x8 qfrag = *(const bf16x8*)&Qb[(size_t)n_s * HD + g*8];

    const int i1w = (q0 >> 5) + (w >> 1);            // wave-uniform i1
    const int j1 = ((w & 1) << 4) | l16;
    const int jA63 = (j1 + 31 - 4*g) * 63;           // row base for sc-even (minus 63r)

    f32x4 oacc[2] = {};
    float l_run = 0.f;

    for (int ph = 0; ph < 8; ++ph) {
        __syncthreads();                              // B0: all reads of prev phase done
        *(bf16x8*)&Ks[kr][kc2] = sregK;
        *(bf16x8*)vdst = sregV;
        __syncthreads();                              // B1: phase tiles visible
        if (ph < 7) {                                 // T14: issue next phase early
            const int m1 = (ph + 1) * 128;
            sregK = *(const bf16x8*)&Kb[(size_t)(m1 + kr) * HD + kc2];
            sregV = *(const bf16x8*)&Vb[(size_t)vd * NN + m1 + vmi];
        }

#pragma unroll
        for (int sub = 0; sub < 2; ++sub) {
            const int it = 2 * ph + sub;
            const bf16 (*Vsp)[72] = sub ? Vs1 : Vs0;
            const int dip = i1w - 2*it + 30;          // in [0,62)
            const unsigned* pAp = &pairTu[0][0] + jA63 + dip;

            f32x4 z[4];
#pragma unroll
            for (int sc = 0; sc < 4; ++sc) {
                bf16x8 kf = *(const bf16x8*)&Ks[sub*64 + sc*16 + l16][g*8];
                f32x4 zz = {0.f, 0.f, 0.f, 0.f};
                z[sc] = MFMA16(kf, qfrag, zz);        // S^T: m-row, n-col
            }

            float p[4][4];
            float lsum = 0.f;
#pragma unroll
            for (int r = 0; r < 4; ++r) {
                const unsigned prA = pAp[-63 * r];            // sc even
                const unsigned prB = pAp[-63 * r - 1008];     // sc odd (dj -= 16)
                float p0 = exp2f(z[0][r] + __uint_as_float(prA << 16));
                float p2 = exp2f(z[2][r] + __uint_as_float(prA & 0xFFFF0000u));
                float p1 = exp2f(z[1][r] + __uint_as_float(prB << 16));
                float p3 = exp2f(z[3][r] + __uint_as_float(prB & 0xFFFF0000u));
                p[0][r] = p0; p[1][r] = p1; p[2][r] = p2; p[3][r] = p3;
                lsum += (p0 + p1) + (p2 + p3);
            }
            l_run += lsum;                            // cross-lane reduce deferred

            // PV with relabeled contraction: slot k=8g+4sh+r <-> m=32kc+16sh+4g+r
#pragma unroll
            for (int kc = 0; kc < 2; ++kc) {
                bf16x8 pa;
#pragma unroll
                for (int r = 0; r < 4; ++r) {
                    pa[r]     = (bf16)p[2*kc][r];
                    pa[4 + r] = (bf16)p[2*kc + 1][r];
                }
#pragma unroll
                for (int ds = 0; ds < 2; ++ds) {
                    const bf16* vrow = &Vsp[ds*16 + l16][kc*32 + 4*g];
                    bf16x4 lo = *(const bf16x4*)vrow;
                    bf16x4 hi = *(const bf16x4*)(vrow + 16);
                    bf16x8 vf = __builtin_shufflevector(lo, hi, 0, 1, 2, 3, 4, 5, 6, 7);
                    oacc[ds] = MFMA16(pa, vf, oacc[ds]);
                }
            }
        }
    }

    // row-sum: lanes sharing l16 (4 g-groups) hold complementary m-slices
    l_run += __shfl_xor(l_run, 16);
    l_run += __shfl_xor(l_run, 32);
    const int sbase = (lane & 48) | ((lane >> 2) & 12);
    float rin[4];
#pragma unroll
    for (int r = 0; r < 4; ++r) rin[r] = 1.0f / __shfl(l_run, sbase + r);

    const int nrow = q0 + w*16 + g*4;
#pragma unroll
    for (int ds = 0; ds < 2; ++ds) {
        const int c = h*HD + ds*16 + l16;
#pragma unroll
        for (int r = 0; r < 4; ++r)
            AOt[((size_t)b*NN + nrow + r) * NC + c] = (bf16)(oacc[ds][r] * rin[r]);
    }
}

// ---------------- output projection GEMM (64x128 tile, reg-prefetch) ----------------
__global__ __launch_bounds__(256) void proj_gemm_kernel(
    const bf16* __restrict__ W, const bf16* __restrict__ AOt,
    const float* __restrict__ bproj, float* __restrict__ out)
{
    __shared__ bf16 As[64][40];
    __shared__ bf16 Bs[128][40];
    const int t = threadIdx.x;
    const int w = t >> 6, lane = t & 63, g = lane >> 4, l16 = lane & 15;
    const int wm = w >> 1, wn = w & 1;
    const int n0g = blockIdx.x * 128;
    const int b = n0g >> 10, n0 = n0g & 1023;
    const int o0 = blockIdx.y * 64;
    const bf16* Ab = AOt + (size_t)b * NN * NC;

    const int ar = t >> 2, ac = (t & 3) * 8;

    f32x4 acc[2][4] = {};

    bf16x8 aw = *(const bf16x8*)&W[(size_t)(o0 + ar) * NC + ac];
    bf16x8 bw[2];
#pragma unroll
    for (int i = 0; i < 2; ++i) {
        const int s = t + i * 256, r = s >> 2, cc = (s & 3) * 8;
        bw[i] = *(const bf16x8*)&Ab[(size_t)(n0 + r) * NC + cc];
    }

    for (int k0 = 0; k0 < NC; k0 += 32) {
        __syncthreads();
        *(bf16x8*)&As[ar][ac] = aw;
#pragma unroll
        for (int i = 0; i < 2; ++i) {
            const int s = t + i * 256, r = s >> 2, cc = (s & 3) * 8;
            *(bf16x8*)&Bs[r][cc] = bw[i];
        }
        __syncthreads();
        if (k0 + 32 < NC) {
            aw = *(const bf16x8*)&W[(size_t)(o0 + ar) * NC + k0 + 32 + ac];
#pragma unroll
            for (int i = 0; i < 2; ++i) {
                const int s = t + i * 256, r = s >> 2, cc = (s & 3) * 8;
                bw[i] = *(const bf16x8*)&Ab[(size_t)(n0 + r) * NC + k0 + 32 + cc];
            }
        }
        bf16x8 a0 = *(const bf16x8*)&As[wm*32      + l16][g*8];
        bf16x8 a1 = *(const bf16x8*)&As[wm*32 + 16 + l16][g*8];
#pragma unroll
        for (int sn = 0; sn < 4; ++sn) {
            bf16x8 bf = *(const bf16x8*)&Bs[wn*64 + sn*16 + l16][g*8];
            acc[0][sn] = MFMA16(a0, bf, acc[0][sn]);
            acc[1][sn] = MFMA16(a1, bf, acc[1][sn]);
        }
    }

#pragma unroll
    for (int sm = 0; sm < 2; ++sm)
#pragma unroll
    for (int sn = 0; sn < 4; ++sn) {
        const int col   = n0 + wn*64 + sn*16 + l16;
        const int obase = o0 + wm*32 + sm*16 + g*4;
        f32x4 v = acc[sm][sn];
#pragma unroll
        for (int r = 0; r < 4; ++r)
            out[((size_t)b*NC + obase + r)*NN + col] = v[r] + bproj[obase + r];
    }
}

extern "C" void kernel_launch(void* const* d_in, const int* in_sizes, int n_in,
                              void* d_out, int out_size, void* d_ws, size_t ws_size,
                              hipStream_t stream)
{
    const float* x          = (const float*)d_in[0];
    const float* wq         = (const float*)d_in[1];
    const float* bq         = (const float*)d_in[2];
    const float* wkv        = (const float*)d_in[3];
    const float* bkv        = (const float*)d_in[4];
    const float* wproj      = (const float*)d_in[5];
    const float* bproj      = (const float*)d_in[6];
    const float* bias_table = (const float*)d_in[7];
    // d_in[8] = rel_index: unused (bias index computed arithmetically in-kernel)
    float* out = (float*)d_out;

    bf16* wsb  = (bf16*)d_ws;
    bf16* Xt   = wsb + XT_OFF;
    bf16* Wqkv = wsb + WQKV_OFF;
    bf16* Wp   = wsb + WP_OFF;
    bf16* Qd   = wsb + Q_OFF;
    bf16* Kd   = wsb + K_OFF;
    bf16* Vd   = wsb + V_OFF;
    bf16* AOt  = wsb + AO_OFF;

    cast_xt_kernel<<<dim3(NB * 96), 256, 0, stream>>>(x, Xt);
    cast_w_kernel<<<dim3((unsigned)((WQKV_N + WP_N)/4/256)), 256, 0, stream>>>(wq, wkv, wproj, Wqkv, Wp);
    qkv_gemm_kernel<<<dim3(64, 18), 256, 0, stream>>>(Wqkv, Xt, bq, bkv, Qd, Kd, Vd);
    attn_kernel<<<dim3(8, 12, 8), 512, 0, stream>>>(Qd, Kd, Vd, bias_table, AOt);
    proj_gemm_kernel<<<dim3(64, 6), 256, 0, stream>>>(Wp, AOt, bproj, out);
}

// Round 6
// 67.403 us; speedup vs baseline: 2.2286x; 1.1949x over previous
//
#include <hip/hip_runtime.h>

typedef __bf16 bf16;
typedef __bf16 bf16x8 __attribute__((ext_vector_type(8)));
typedef __bf16 bf16x4 __attribute__((ext_vector_type(4)));
typedef float  f32x4  __attribute__((ext_vector_type(4)));

static constexpr int NB = 8;      // batch
static constexpr int NH = 12;     // heads
static constexpr int HD = 32;     // head dim
static constexpr int NN = 1024;   // tokens (32x32)
static constexpr int NC = 384;    // channels
static constexpr int NTBL = 3969; // (2*32-1)^2

static constexpr float LOG2E = 1.4426950408889634f;
static constexpr float QSC   = (float)(0.17677669529663687 * 1.4426950408889634); // scale*log2e

static constexpr size_t XT_N   = (size_t)NB*NN*NC;    // x transposed [b][n][c] bf16
static constexpr size_t WQKV_N = (size_t)3*NC*NC;
static constexpr size_t WP_N   = (size_t)NC*NC;
static constexpr size_t QKV_N  = (size_t)NB*NH*NN*HD;

static constexpr size_t XT_OFF   = 0;
static constexpr size_t WQKV_OFF = XT_OFF + XT_N;
static constexpr size_t WP_OFF   = WQKV_OFF + WQKV_N;
static constexpr size_t Q_OFF    = WP_OFF + WP_N;
static constexpr size_t K_OFF    = Q_OFF + QKV_N;
static constexpr size_t V_OFF    = K_OFF + QKV_N;
static constexpr size_t AO_OFF   = V_OFF + QKV_N;     // [b][n][c] bf16

#define MFMA16(a,b,c) __builtin_amdgcn_mfma_f32_16x16x32_bf16(a,b,c,0,0,0)

static __device__ inline float fast_exp2(float x) {
#if __has_builtin(__builtin_amdgcn_exp2f)
    return __builtin_amdgcn_exp2f(x);
#else
    return exp2f(x);
#endif
}

// ---------------- merged cast: x transpose + weights ----------------
// blocks [0,768): [b][c][n] f32 -> [b][n][c] bf16 ; blocks [768,1344): weights
__global__ __launch_bounds__(256) void cast_all_kernel(const float* __restrict__ x,
                                                       const float* __restrict__ wq,
                                                       const float* __restrict__ wkv,
                                                       const float* __restrict__ wproj,
                                                       bf16* __restrict__ xt,
                                                       bf16* __restrict__ wqkv,
                                                       bf16* __restrict__ wp)
{
    __shared__ bf16 T[64][68];
    const int t = threadIdx.x;
    if (blockIdx.x >= 768) {
        const size_t i = ((size_t)(blockIdx.x - 768) * 256 + t) * 4;
        if (i >= WQKV_N + WP_N) return;
        const float* src; bf16* dst;
        if (i < (size_t)NC*NC)      { src = wq + i;                     dst = wqkv + i; }
        else if (i < WQKV_N)        { src = wkv + (i - (size_t)NC*NC);  dst = wqkv + i; }
        else                        { src = wproj + (i - WQKV_N);       dst = wp + (i - WQKV_N); }
        float4 v = *(const float4*)src;
        bf16x4 o; o[0] = (bf16)v.x; o[1] = (bf16)v.y; o[2] = (bf16)v.z; o[3] = (bf16)v.w;
        *(bf16x4*)dst = o;
        return;
    }
    const int bid = blockIdx.x;            // b*96 + ct*16 + nt
    const int b = bid / 96, rem = bid % 96, ct = rem >> 4, nt = rem & 15;
    const int c0 = ct * 64, n0 = nt * 64;
    const float* Xb = x + (size_t)b * NC * NN;
    const int nl = t & 63, c4 = (t >> 6) * 4;
#pragma unroll
    for (int i = 0; i < 4; ++i) {
        const int c = c4 + i * 16;
        bf16x4 v;
#pragma unroll
        for (int j = 0; j < 4; ++j)
            v[j] = (bf16)Xb[(size_t)(c0 + c + j) * NN + n0 + nl];  // coalesced over nl
        *(bf16x4*)&T[nl][c] = v;
    }
    __syncthreads();
    const int n = t >> 2;
#pragma unroll
    for (int i = 0; i < 2; ++i) {
        const int cg = (t & 3) * 8 + i * 32;
        bf16x4 a = *(const bf16x4*)&T[n][cg];
        bf16x4 bv = *(const bf16x4*)&T[n][cg + 4];
        bf16x8 vv = __builtin_shufflevector(a, bv, 0, 1, 2, 3, 4, 5, 6, 7);
        *(bf16x8*)&xt[((size_t)b * NN + n0 + n) * NC + c0 + cg] = vv;
    }
}

// ---------------- QKV projection GEMM (64x128 tile, reg-prefetch) ----------------
__global__ __launch_bounds__(256) void qkv_gemm_kernel(
    const bf16* __restrict__ W, const bf16* __restrict__ Xt,
    const float* __restrict__ bq, const float* __restrict__ bkv,
    bf16* __restrict__ Qd, bf16* __restrict__ Kd, bf16* __restrict__ Vd)
{
    __shared__ bf16 As[64][40];    // [o][c]
    __shared__ bf16 Bs[128][40];   // [n][c]
    const int t = threadIdx.x;
    const int w = t >> 6, lane = t & 63, g = lane >> 4, l16 = lane & 15;
    const int wm = w >> 1, wn = w & 1;
    const int n0g = blockIdx.x * 128;
    const int b = n0g >> 10, n0 = n0g & 1023;
    const int o0 = blockIdx.y * 64;
    const bf16* Xb = Xt + (size_t)b * NN * NC;

    const int ar = t >> 2, ac = (t & 3) * 8;

    f32x4 acc[2][4] = {};

    bf16x8 aw = *(const bf16x8*)&W[(size_t)(o0 + ar) * NC + ac];
    bf16x8 bw[2];
#pragma unroll
    for (int i = 0; i < 2; ++i) {
        const int s = t + i * 256, r = s >> 2, cc = (s & 3) * 8;
        bw[i] = *(const bf16x8*)&Xb[(size_t)(n0 + r) * NC + cc];
    }

    for (int k0 = 0; k0 < NC; k0 += 32) {
        __syncthreads();
        *(bf16x8*)&As[ar][ac] = aw;
#pragma unroll
        for (int i = 0; i < 2; ++i) {
            const int s = t + i * 256, r = s >> 2, cc = (s & 3) * 8;
            *(bf16x8*)&Bs[r][cc] = bw[i];
        }
        __syncthreads();
        if (k0 + 32 < NC) {        // early-issue next k-tile (hides under MFMA)
            aw = *(const bf16x8*)&W[(size_t)(o0 + ar) * NC + k0 + 32 + ac];
#pragma unroll
            for (int i = 0; i < 2; ++i) {
                const int s = t + i * 256, r = s >> 2, cc = (s & 3) * 8;
                bw[i] = *(const bf16x8*)&Xb[(size_t)(n0 + r) * NC + k0 + 32 + cc];
            }
        }
        bf16x8 a0 = *(const bf16x8*)&As[wm*32      + l16][g*8];
        bf16x8 a1 = *(const bf16x8*)&As[wm*32 + 16 + l16][g*8];
#pragma unroll
        for (int sn = 0; sn < 4; ++sn) {
            bf16x8 bf = *(const bf16x8*)&Bs[wn*64 + sn*16 + l16][g*8];
            acc[0][sn] = MFMA16(a0, bf, acc[0][sn]);
            acc[1][sn] = MFMA16(a1, bf, acc[1][sn]);
        }
    }

#pragma unroll
    for (int sm = 0; sm < 2; ++sm)
#pragma unroll
    for (int sn = 0; sn < 4; ++sn) {
        const int col   = n0 + wn*64 + sn*16 + l16;
        const int obase = o0 + wm*32 + sm*16 + g*4;
        f32x4 v = acc[sm][sn];
        if (obase < 384) {
            const int hh = obase >> 5, d = obase & 31;
            bf16x4 o4;
#pragma unroll
            for (int r = 0; r < 4; ++r) o4[r] = (bf16)((v[r] + bq[obase + r]) * QSC);
            *(bf16x4*)&Qd[(((size_t)b*NH + hh)*NN + col)*HD + d] = o4;
        } else if (obase < 768) {
            const int oo = obase - 384; const int hh = oo >> 5, d = oo & 31;
            bf16x4 o4;
#pragma unroll
            for (int r = 0; r < 4; ++r) o4[r] = (bf16)(v[r] + bkv[oo + r]);
            *(bf16x4*)&Kd[(((size_t)b*NH + hh)*NN + col)*HD + d] = o4;
        } else {
            const int oo = obase - 768; const int hh = oo >> 5, d = oo & 31;
#pragma unroll
            for (int r = 0; r < 4; ++r)
                Vd[(((size_t)b*NH + hh)*HD + d + r)*NN + col] = (bf16)(v[r] + bkv[obase - 384 + r]);
        }
    }
}

// ---------------- fused flash attention ----------------
// 512 threads (8 waves), QBLK=128, 128 keys per barrier phase (2 x 64 sub-tiles).
// r5-proven schedule: B0 -> ds_write staged regs -> B1 -> issue next loads -> compute.
// New this round: bias folded into QK^T MFMA accumulator; row-sum l via extra
// ones-MFMA (idle MFMA pipe) in output layout (no epilogue shuffles); V stored
// in k-slot-permuted order so PV B-frag is a single ds_read_b128; pairTu built
// directly from global (no bsc) -> LDS 35.3KB -> 4 blocks/CU; XCD-swizzled grid.
__global__ __launch_bounds__(512, 8) void attn_kernel(
    const bf16* __restrict__ Qg, const bf16* __restrict__ Kg, const bf16* __restrict__ Vg,
    const float* __restrict__ bias_table, bf16* __restrict__ AOt)
{
    __shared__ unsigned int pairTu[63][63];  // [dj][dip]: lo16=bf16 bias(dip+1 row), hi16=bias(dip row)
    __shared__ bf16 Ks[128][40];             // [m][d] stride 80B (odd x16B)
    __shared__ bf16 Vs[2][32][72];           // [sub][d][q] q = permuted m (see below)

    const int t = threadIdx.x;
    const int w = t >> 6, lane = t & 63, g = lane >> 4, l16 = lane & 15;

    // XCD-aware swizzle: 768 blocks, 8 XCDs -> each XCD owns 12 (h,b) pairs
    const int bid = blockIdx.x;
    const int nid = (bid & 7) * 96 + (bid >> 3);
    const int qt = nid & 7;
    const int hb = nid >> 3;
    const int h = hb % 12, b = hb / 12;

    const bf16* Qb = Qg + ((size_t)(b*NH + h)) * NN * HD;
    const bf16* Kb = Kg + ((size_t)(b*NH + h)) * NN * HD;
    const bf16* Vb = Vg + ((size_t)(b*NH + h)) * HD * NN;

    // staging slots
    const int kr = t >> 2, kc2 = (t & 3) * 8;         // K: 128 rows x 4 col-chunks
    const int vd = t >> 4, vmi = (t & 15) * 8;        // V: 32 d x 16 m-chunks
    const int vsub = vmi >> 6, vmm = vmi & 63;
    const int vqa = ((vmm >> 5) & 1) * 32 + ((vmm >> 2) & 3) * 8 + ((vmm >> 4) & 1) * 4;

    // issue phase-0 loads first (latency hides under pairTu build)
    bf16x8 sregK = *(const bf16x8*)&Kb[(size_t)kr * HD + kc2];
    bf16x8 sregV = *(const bf16x8*)&Vb[(size_t)vd * NN + vmi];

    const int q0 = qt * 128;
    const int n_s = q0 + w*16 + l16;                 // this lane's softmax row
    const bf16x8 qfrag = *(const bf16x8*)&Qb[(size_t)n_s * HD + g*8];

    // build packed bias pair-table straight from global (L2-resident)
    for (int idx = t; idx < 63 * 62; idx += 512) {
        const int dj = idx / 62, dip = idx % 62;
        bf16 lo = (bf16)(bias_table[(size_t)((dip + 1) * 63 + dj) * NH + h] * LOG2E);
        bf16 hi = (bf16)(bias_table[(size_t)(dip * 63 + dj) * NH + h] * LOG2E);
        pairTu[dj][dip] = (unsigned)__builtin_bit_cast(unsigned short, lo)
                        | ((unsigned)__builtin_bit_cast(unsigned short, hi) << 16);
    }
    // visible after the loop's first two barriers

    const int i1w = (q0 >> 5) + (w >> 1);            // wave-uniform i1
    const int j1 = ((w & 1) << 4) | l16;
    const int jA63 = (j1 + 31 - 4*g) * 63;           // dj row base (minus 63r later)

    bf16x8 vones;
#pragma unroll
    for (int e = 0; e < 8; ++e) vones[e] = (bf16)1.0f;

    f32x4 oacc[2] = {};
    f32x4 oacc_l = {};                               // row-sums via ones-MFMA

    for (int ph = 0; ph < 8; ++ph) {
        __syncthreads();                              // B0: all reads of prev phase done
        *(bf16x8*)&Ks[kr][kc2] = sregK;
        { bf16x4 vlo = __builtin_shufflevector(sregV, sregV, 0, 1, 2, 3);
          bf16x4 vhi = __builtin_shufflevector(sregV, sregV, 4, 5, 6, 7);
          *(bf16x4*)&Vs[vsub][vd][vqa]     = vlo;     // m=32kc+4g+r   (sh=0..)
          *(bf16x4*)&Vs[vsub][vd][vqa + 8] = vhi; }   // next g group
        __syncthreads();                              // B1: phase tiles visible
        if (ph < 7) {                                 // T14: issue next phase early
            const int m1 = (ph + 1) * 128;
            sregK = *(const bf16x8*)&Kb[(size_t)(m1 + kr) * HD + kc2];
            sregV = *(const bf16x8*)&Vb[(size_t)vd * NN + m1 + vmi];
        }

#pragma unroll
        for (int sub = 0; sub < 2; ++sub) {
            const int it = 2 * ph + sub;
            const bf16 (*Vsp)[72] = Vs[sub];
            const int dip = i1w - 2*it + 30;          // in [0,62)
            const unsigned* pAp = &pairTu[0][0] + jA63 + dip;

            // bias accumulators: bacc[sc][r] = bias for (m=16sc+4g+r, n=n_s)
            f32x4 bacc[4];
#pragma unroll
            for (int r = 0; r < 4; ++r) {
                const unsigned prA = pAp[-63 * r];            // sc even
                const unsigned prB = pAp[-63 * r - 1008];     // sc odd (dj -= 16)
                bacc[0][r] = __uint_as_float(prA << 16);
                bacc[2][r] = __uint_as_float(prA & 0xFFFF0000u);
                bacc[1][r] = __uint_as_float(prB << 16);
                bacc[3][r] = __uint_as_float(prB & 0xFFFF0000u);
            }

            float p[4][4];
#pragma unroll
            for (int sc = 0; sc < 4; ++sc) {
                bf16x8 kf = *(const bf16x8*)&Ks[sub*64 + sc*16 + l16][g*8];
                f32x4 z = MFMA16(kf, qfrag, bacc[sc]);    // S^T + bias
#pragma unroll
                for (int r = 0; r < 4; ++r) p[sc][r] = fast_exp2(z[r]);
            }

            // PV with relabeled contraction: slot k=8g+4sh+r <-> m=32kc+16sh+4g+r
#pragma unroll
            for (int kc = 0; kc < 2; ++kc) {
                bf16x8 pa;
#pragma unroll
                for (int r = 0; r < 4; ++r) {
                    pa[r]     = (bf16)p[2*kc][r];
                    pa[4 + r] = (bf16)p[2*kc + 1][r];
                }
#pragma unroll
                for (int ds = 0; ds < 2; ++ds) {
                    bf16x8 vf = *(const bf16x8*)&Vsp[ds*16 + l16][kc*32 + 8*g];
                    oacc[ds] = MFMA16(pa, vf, oacc[ds]);
                }
                oacc_l = MFMA16(pa, vones, oacc_l);   // row-sums on idle MFMA pipe
            }
        }
    }

    // oacc_l[r] = full row sum for row nrow+r (replicated across l16) -> no shuffles
    float rin[4];
#pragma unroll
    for (int r = 0; r < 4; ++r) rin[r] = 1.0f / oacc_l[r];

    const int nrow = q0 + w*16 + g*4;
#pragma unroll
    for (int ds = 0; ds < 2; ++ds) {
        const int c = h*HD + ds*16 + l16;
#pragma unroll
        for (int r = 0; r < 4; ++r)
            AOt[((size_t)b*NN + nrow + r) * NC + c] = (bf16)(oacc[ds][r] * rin[r]);
    }
}

// ---------------- output projection GEMM (64x128 tile, reg-prefetch) ----------------
__global__ __launch_bounds__(256) void proj_gemm_kernel(
    const bf16* __restrict__ W, const bf16* __restrict__ AOt,
    const float* __restrict__ bproj, float* __restrict__ out)
{
    __shared__ bf16 As[64][40];
    __shared__ bf16 Bs[128][40];
    const int t = threadIdx.x;
    const int w = t >> 6, lane = t & 63, g = lane >> 4, l16 = lane & 15;
    const int wm = w >> 1, wn = w & 1;
    const int n0g = blockIdx.x * 128;
    const int b = n0g >> 10, n0 = n0g & 1023;
    const int o0 = blockIdx.y * 64;
    const bf16* Ab = AOt + (size_t)b * NN * NC;

    const int ar = t >> 2, ac = (t & 3) * 8;

    f32x4 acc[2][4] = {};

    bf16x8 aw = *(const bf16x8*)&W[(size_t)(o0 + ar) * NC + ac];
    bf16x8 bw[2];
#pragma unroll
    for (int i = 0; i < 2; ++i) {
        const int s = t + i * 256, r = s >> 2, cc = (s & 3) * 8;
        bw[i] = *(const bf16x8*)&Ab[(size_t)(n0 + r) * NC + cc];
    }

    for (int k0 = 0; k0 < NC; k0 += 32) {
        __syncthreads();
        *(bf16x8*)&As[ar][ac] = aw;
#pragma unroll
        for (int i = 0; i < 2; ++i) {
            const int s = t + i * 256, r = s >> 2, cc = (s & 3) * 8;
            *(bf16x8*)&Bs[r][cc] = bw[i];
        }
        __syncthreads();
        if (k0 + 32 < NC) {
            aw = *(const bf16x8*)&W[(size_t)(o0 + ar) * NC + k0 + 32 + ac];
#pragma unroll
            for (int i = 0; i < 2; ++i) {
                const int s = t + i * 256, r = s >> 2, cc = (s & 3) * 8;
                bw[i] = *(const bf16x8*)&Ab[(size_t)(n0 + r) * NC + k0 + 32 + cc];
            }
        }
        bf16x8 a0 = *(const bf16x8*)&As[wm*32      + l16][g*8];
        bf16x8 a1 = *(const bf16x8*)&As[wm*32 + 16 + l16][g*8];
#pragma unroll
        for (int sn = 0; sn < 4; ++sn) {
            bf16x8 bf = *(const bf16x8*)&Bs[wn*64 + sn*16 + l16][g*8];
            acc[0][sn] = MFMA16(a0, bf, acc[0][sn]);
            acc[1][sn] = MFMA16(a1, bf, acc[1][sn]);
        }
    }

#pragma unroll
    for (int sm = 0; sm < 2; ++sm)
#pragma unroll
    for (int sn = 0; sn < 4; ++sn) {
        const int col   = n0 + wn*64 + sn*16 + l16;
        const int obase = o0 + wm*32 + sm*16 + g*4;
        f32x4 v = acc[sm][sn];
#pragma unroll
        for (int r = 0; r < 4; ++r)
            out[((size_t)b*NC + obase + r)*NN + col] = v[r] + bproj[obase + r];
    }
}

extern "C" void kernel_launch(void* const* d_in, const int* in_sizes, int n_in,
                              void* d_out, int out_size, void* d_ws, size_t ws_size,
                              hipStream_t stream)
{
    const float* x          = (const float*)d_in[0];
    const float* wq         = (const float*)d_in[1];
    const float* bq         = (const float*)d_in[2];
    const float* wkv        = (const float*)d_in[3];
    const float* bkv        = (const float*)d_in[4];
    const float* wproj      = (const float*)d_in[5];
    const float* bproj      = (const float*)d_in[6];
    const float* bias_table = (const float*)d_in[7];
    // d_in[8] = rel_index: unused (bias index computed arithmetically in-kernel)
    float* out = (float*)d_out;

    bf16* wsb  = (bf16*)d_ws;
    bf16* Xt   = wsb + XT_OFF;
    bf16* Wqkv = wsb + WQKV_OFF;
    bf16* Wp   = wsb + WP_OFF;
    bf16* Qd   = wsb + Q_OFF;
    bf16* Kd   = wsb + K_OFF;
    bf16* Vd   = wsb + V_OFF;
    bf16* AOt  = wsb + AO_OFF;

    cast_all_kernel<<<dim3(768 + 576), 256, 0, stream>>>(x, wq, wkv, wproj, Xt, Wqkv, Wp);
    qkv_gemm_kernel<<<dim3(64, 18), 256, 0, stream>>>(Wqkv, Xt, bq, bkv, Qd, Kd, Vd);
    attn_kernel<<<dim3(768), 512, 0, stream>>>(Qd, Kd, Vd, bias_table, AOt);
    proj_gemm_kernel<<<dim3(64, 6), 256, 0, stream>>>(Wp, AOt, bproj, out);
}